// Round 6
// baseline (126.091 us; speedup 1.0000x reference)
//
#include <hip/hip_runtime.h>
#include <hip/hip_bf16.h>
#include <hip/hip_cooperative_groups.h>

namespace cg = cooperative_groups;

#define B_N 4096
#define E_N 64
#define D_N 1024
#define ROWS 16

typedef __bf16 bf16x8 __attribute__((ext_vector_type(8)));
typedef __bf16 bf16x4 __attribute__((ext_vector_type(4)));
typedef float f32x4 __attribute__((ext_vector_type(4)));

// ws layout (bytes):
// [0, 256)         Ak     (64 f32)
// [256, 131328)    sk_bf16 [64][1024]   (sigma_inv * keys, K-major)
// [131328, 262400) kT_bf16 [1024][64]   (raw keys transposed, K(=e)-major)

// Single fused cooperative kernel, grid 256 x 1024 thr (1 block/CU, 4 w/SIMD).
// Phase A (pre grid-sync): all blocks compute sinv locally; blocks 0..63 also
// write sk[e] + reduce ak[e]; blocks 64..79 transpose one 64-d slab into kT.
// All blocks stage z (HBM) — duty work hides under it. grid.sync() makes
// sk/kT/ak visible device-wide, then the proven R5 GEMM1/softmax/GEMM2 runs.
__global__ __launch_bounds__(1024) void fused_kernel(
    const float* __restrict__ z, const float* __restrict__ keys,
    const float* __restrict__ lsig,
    float* __restrict__ ak, __bf16* __restrict__ sk, __bf16* __restrict__ kT,
    float* __restrict__ out_sim, float* __restrict__ out_we)
{
  constexpr int ZS = D_N + 8;            // bf16 elems; 16B-aligned rows
  __shared__ float sinv_lds[D_N];        // 4 KB
  __shared__ float red[16];
  __shared__ __bf16 tl[64][72];          // transpose tile, +8 pad (9 KB)
  __shared__ __bf16 zlds[ROWS * ZS];     // 33 KB
  __shared__ float azs[ROWS];
  __shared__ float pacc[4][4][16][20];   // [kq][et][row][ln], +4 pad; 20 KB
  __shared__ __bf16 wlds[ROWS][72];      // +8 pad

  const int t   = threadIdx.x;
  const int bid = blockIdx.x;
  const int b0  = bid * ROWS;

  const int wave = t >> 6;               // 0..15
  const int lane = t & 63;
  const int ln = lane & 15;
  const int q  = lane >> 4;
  const int et = wave & 3;               // expert tile 0..3
  const int kq = wave >> 2;              // K-quarter 0..3

  // ---------- sinv (every block, local) ----------
  sinv_lds[t] = __expf(-lsig[t]);
  __syncthreads();

  // ---------- distributed prep duties (overlap with z-stage below) ----------
  if (bid < 64) {
    // sk[e] = bf16(sinv*keys[e]); ak[e] = sum sinv*k^2
    const int e = bid;
    const float k = keys[(size_t)e * D_N + t];
    const float s = sinv_lds[t];
    sk[(size_t)e * D_N + t] = (__bf16)(s * k);
    float p = s * k * k;
    #pragma unroll
    for (int off = 32; off > 0; off >>= 1) p += __shfl_down(p, off);
    if (lane == 0) red[wave] = p;
    __syncthreads();
    if (t == 0) {
      float a = 0.f;
      #pragma unroll
      for (int i = 0; i < 16; ++i) a += red[i];
      ak[e] = a;
    }
  } else if (bid < 80) {
    // transpose one 64-d slab: kT[d][e] = bf16(keys[e][d])
    const int d0 = (bid - 64) * 64;
    const int e  = t >> 4;               // 0..63
    const int dd = (t & 15) * 4;
    const float4 k4 = *(const float4*)(keys + (size_t)e * D_N + d0 + dd);
    tl[dd + 0][e] = (__bf16)k4.x; tl[dd + 1][e] = (__bf16)k4.y;
    tl[dd + 2][e] = (__bf16)k4.z; tl[dd + 3][e] = (__bf16)k4.w;
    __syncthreads();
    if (t < 512) {
      const int d8 = t >> 3;             // 0..63
      const int l8 = t & 7;
      const bf16x8 v = *(const bf16x8*)&tl[d8][l8 * 8];
      *(bf16x8*)(kT + (size_t)(d0 + d8) * E_N + l8 * 8) = v;
    }
  }

  // ---------- stage z -> bf16 LDS; Az = sum s*z^2 (one wave per row) ----------
  const int sr = wave;                   // row 0..15
  const int sc = lane;                   // 0..63
  const float* zrow = z + (size_t)(b0 + sr) * D_N;
  float az = 0.f;
  #pragma unroll
  for (int l = 0; l < 4; ++l) {
    const int c = sc * 4 + l * 256;
    const float4 z4 = *(const float4*)(zrow + c);
    const f32x4 s4 = *(const f32x4*)(&sinv_lds[c]);
    az += s4[0] * z4.x * z4.x + s4[1] * z4.y * z4.y + s4[2] * z4.z * z4.z + s4[3] * z4.w * z4.w;
    bf16x4 zb;
    zb[0] = (__bf16)z4.x; zb[1] = (__bf16)z4.y; zb[2] = (__bf16)z4.z; zb[3] = (__bf16)z4.w;
    *(bf16x4*)(&zlds[sr * ZS + c]) = zb;
  }
  // full-wave butterfly reduce; lane 0 publishes
  az += __shfl_xor(az, 1);  az += __shfl_xor(az, 2);
  az += __shfl_xor(az, 4);  az += __shfl_xor(az, 8);
  az += __shfl_xor(az, 16); az += __shfl_xor(az, 32);
  if (sc == 0) azs[sr] = az;

  // ---------- grid-wide sync: sk/kT/ak visible device-wide ----------
  cg::this_grid().sync();

  // softmax threads pull their ak quad now; latency hides under GEMM1
  f32x4 ak4 = {0.f, 0.f, 0.f, 0.f};
  if (t < 256) ak4 = *(const f32x4*)(ak + (t & 15) * 4);

  // ---------- GEMM1 (split-K quarters): 16 experts x 256 K per wave ----------
  const __bf16* bp = sk + (size_t)(et * 16 + ln) * D_N + kq * 256 + q * 8;
  const __bf16* ap = &zlds[ln * ZS + kq * 256 + q * 8];
  f32x4 acc = {0.f, 0.f, 0.f, 0.f};
  #pragma unroll
  for (int ks = 0; ks < 8; ++ks) {
    const bf16x8 bfr = *(const bf16x8*)(bp + ks * 32);
    const bf16x8 afr = *(const bf16x8*)(ap + ks * 32);
    acc = __builtin_amdgcn_mfma_f32_16x16x32_bf16(afr, bfr, acc, 0, 0, 0);
  }
  // publish partials (write pattern is 2-way bank alias only — free)
  #pragma unroll
  for (int i = 0; i < 4; ++i) pacc[kq][et][q * 4 + i][ln] = acc[i];

  __syncthreads();                       // pacc ready

  // ---------- fused combine + similarity store + softmax (256 threads) ----------
  // 16 rows x 16 threads; thread handles experts seg*4 .. seg*4+3
  if (t < 256) {
    const int row = t >> 4, seg = t & 15;
    const int pe = seg >> 2, pc = (seg & 3) * 4;
    f32x4 p = *(const f32x4*)&pacc[0][pe][row][pc];
    #pragma unroll
    for (int k = 1; k < 4; ++k) {
      const f32x4 pk = *(const f32x4*)&pacc[k][pe][row][pc];
      p[0] += pk[0]; p[1] += pk[1]; p[2] += pk[2]; p[3] += pk[3];
    }
    const float azr = azs[row];
    f32x4 s;
    #pragma unroll
    for (int j = 0; j < 4; ++j) {
      const float dist = azr + ak4[j] - 2.0f * p[j];
      s[j] = 1.0f / (1.0f + dist);
    }
    *(f32x4*)(out_sim + (size_t)(b0 + row) * E_N + seg * 4) = s;
    float mx = fmaxf(fmaxf(s[0], s[1]), fmaxf(s[2], s[3]));
    mx = fmaxf(mx, __shfl_xor(mx, 1));
    mx = fmaxf(mx, __shfl_xor(mx, 2));
    mx = fmaxf(mx, __shfl_xor(mx, 4));
    mx = fmaxf(mx, __shfl_xor(mx, 8));
    float v[4];
    float sum = 0.f;
    #pragma unroll
    for (int j = 0; j < 4; ++j) { v[j] = __expf(s[j] - mx); sum += v[j]; }
    sum += __shfl_xor(sum, 1);
    sum += __shfl_xor(sum, 2);
    sum += __shfl_xor(sum, 4);
    sum += __shfl_xor(sum, 8);
    const float inv = 1.0f / sum;
    bf16x4 wq;
    #pragma unroll
    for (int j = 0; j < 4; ++j) wq[j] = (__bf16)(v[j] * inv);
    *(bf16x4*)&wlds[row][seg * 4] = wq;
  }
  __syncthreads();                       // wlds ready

  // ---------- GEMM2: out[16 rows][1024] = w[16][64] @ keys[64][1024] ----------
  const bf16x8 a0 = *(const bf16x8*)&wlds[ln][q * 8];        // A: m=row, k=e
  const bf16x8 a1 = *(const bf16x8*)&wlds[ln][32 + q * 8];
  #pragma unroll
  for (int i = 0; i < 4; ++i) {
    const int dt = wave + 16 * i;
    const int d0 = dt * 16;
    const __bf16* kp = kT + (size_t)(d0 + ln) * E_N + q * 8;
    const bf16x8 b0f = *(const bf16x8*)(kp);
    const bf16x8 b1f = *(const bf16x8*)(kp + 32);
    f32x4 o = {0.f, 0.f, 0.f, 0.f};
    o = __builtin_amdgcn_mfma_f32_16x16x32_bf16(a0, b0f, o, 0, 0, 0);
    o = __builtin_amdgcn_mfma_f32_16x16x32_bf16(a1, b1f, o, 0, 0, 0);
    #pragma unroll
    for (int j = 0; j < 4; ++j)
      out_we[(size_t)(b0 + q * 4 + j) * D_N + d0 + ln] = o[j];
  }
}

extern "C" void kernel_launch(void* const* d_in, const int* in_sizes, int n_in,
                              void* d_out, int out_size, void* d_ws, size_t ws_size,
                              hipStream_t stream)
{
  const float* z    = (const float*)d_in[0];
  const float* keys = (const float*)d_in[1];
  const float* ls   = (const float*)d_in[2];
  float* out_sim = (float*)d_out;
  float* out_we  = out_sim + (size_t)B_N * E_N;
  char* ws = (char*)d_ws;
  float*  ak   = (float*)(ws);
  __bf16* sk   = (__bf16*)(ws + 256);
  __bf16* kT   = (__bf16*)(ws + 131328);

  void* args[] = { (void*)&z, (void*)&keys, (void*)&ls,
                   (void*)&ak, (void*)&sk, (void*)&kT,
                   (void*)&out_sim, (void*)&out_we };
  hipLaunchCooperativeKernel((void*)fused_kernel,
                             dim3(B_N / ROWS), dim3(1024),
                             args, 0, stream);
}

// Round 7
// 90.668 us; speedup vs baseline: 1.3907x; 1.3907x over previous
//
#include <hip/hip_runtime.h>
#include <hip/hip_bf16.h>

#define B_N 4096
#define E_N 64
#define D_N 1024
#define ROWS 16

typedef __bf16 bf16x8 __attribute__((ext_vector_type(8)));
typedef __bf16 bf16x4 __attribute__((ext_vector_type(4)));
typedef float f32x4 __attribute__((ext_vector_type(4)));

// Single self-sufficient kernel, grid 256 x 1024 thr (1 block/CU, 4 w/SIMD).
// No prep kernel, no grid sync, no workspace: keys is 256 KB (L2-resident),
// so each block derives sk/kT/ak on the fly:
//   GEMM1 B-frag = bf16(sinv*keys)  (f32 load + LDS sinv + cvt)
//   GEMM2 B-frag = bf16(keys^T)     (strided f32 column loads + cvt)
//   ak[e] computed per-block from keys (64 FMA/thread + shfl reduce)
// Numerically identical bf16 inputs to the two-kernel version; f32
// reductions reorder only.
__global__ __launch_bounds__(1024) void fused_kernel(
    const float* __restrict__ z, const float* __restrict__ keys,
    const float* __restrict__ lsig,
    float* __restrict__ out_sim, float* __restrict__ out_we)
{
  constexpr int ZS = D_N + 8;            // bf16 elems; 16B-aligned rows
  __shared__ float sinv_lds[D_N];        // 4 KB
  __shared__ float aklds[E_N];           // 256 B
  __shared__ __bf16 zlds[ROWS * ZS];     // 33 KB
  __shared__ float azs[ROWS];
  __shared__ float pacc[4][4][16][20];   // [kq][et][row][ln], +4 pad; 20 KB
  __shared__ __bf16 wlds[ROWS][72];      // +8 pad

  const int t   = threadIdx.x;
  const int b0  = blockIdx.x * ROWS;

  const int wave = t >> 6;               // 0..15
  const int lane = t & 63;
  const int ln = lane & 15;
  const int q  = lane >> 4;
  const int et = wave & 3;               // expert tile 0..3
  const int kq = wave >> 2;              // K-quarter 0..3

  // ---------- sinv (local) ----------
  sinv_lds[t] = __expf(-lsig[t]);
  __syncthreads();

  // ---------- ak[e] = sum_d sinv[d]*keys[e][d]^2 (16 threads per expert) ----------
  {
    const int e   = t >> 4;              // 0..63
    const int seg = t & 15;              // d-chunk of 64
    const float* kre = keys + (size_t)e * D_N + seg * 64;
    const float* sre = sinv_lds + seg * 64;
    float pa = 0.f;
    #pragma unroll
    for (int l = 0; l < 16; ++l) {
      const float4 k4 = *(const float4*)(kre + l * 4);
      const f32x4  s4 = *(const f32x4*)(sre + l * 4);
      pa += s4[0] * k4.x * k4.x + s4[1] * k4.y * k4.y
          + s4[2] * k4.z * k4.z + s4[3] * k4.w * k4.w;
    }
    // reduce the 16 contiguous lanes of this expert
    pa += __shfl_xor(pa, 1); pa += __shfl_xor(pa, 2);
    pa += __shfl_xor(pa, 4); pa += __shfl_xor(pa, 8);
    if (seg == 0) aklds[e] = pa;
  }

  // ---------- stage z -> bf16 LDS; Az = sum s*z^2 (one wave per row) ----------
  const int sr = wave;                   // row 0..15
  const int sc = lane;                   // 0..63
  const float* zrow = z + (size_t)(b0 + sr) * D_N;
  float az = 0.f;
  #pragma unroll
  for (int l = 0; l < 4; ++l) {
    const int c = sc * 4 + l * 256;
    const float4 z4 = *(const float4*)(zrow + c);
    const f32x4 s4 = *(const f32x4*)(&sinv_lds[c]);
    az += s4[0] * z4.x * z4.x + s4[1] * z4.y * z4.y + s4[2] * z4.z * z4.z + s4[3] * z4.w * z4.w;
    bf16x4 zb;
    zb[0] = (__bf16)z4.x; zb[1] = (__bf16)z4.y; zb[2] = (__bf16)z4.z; zb[3] = (__bf16)z4.w;
    *(bf16x4*)(&zlds[sr * ZS + c]) = zb;
  }
  az += __shfl_xor(az, 1);  az += __shfl_xor(az, 2);
  az += __shfl_xor(az, 4);  az += __shfl_xor(az, 8);
  az += __shfl_xor(az, 16); az += __shfl_xor(az, 32);
  if (sc == 0) azs[sr] = az;

  __syncthreads();                       // zlds + azs + aklds ready

  // ---------- GEMM1 (split-K quarters): 16 experts x 256 K per wave ----------
  // B-frag built on the fly: bf16(sinv*keys), identical to old sk.
  const float* kbase = keys + (size_t)(et * 16 + ln) * D_N + kq * 256 + q * 8;
  const float* sbase = sinv_lds + kq * 256 + q * 8;
  const __bf16* ap = &zlds[ln * ZS + kq * 256 + q * 8];
  f32x4 acc = {0.f, 0.f, 0.f, 0.f};
  #pragma unroll
  for (int ks = 0; ks < 8; ++ks) {
    const float4 kA = *(const float4*)(kbase + ks * 32);
    const float4 kB = *(const float4*)(kbase + ks * 32 + 4);
    const f32x4  sA = *(const f32x4*)(sbase + ks * 32);
    const f32x4  sB = *(const f32x4*)(sbase + ks * 32 + 4);
    bf16x8 bfr;
    bfr[0] = (__bf16)(sA[0] * kA.x); bfr[1] = (__bf16)(sA[1] * kA.y);
    bfr[2] = (__bf16)(sA[2] * kA.z); bfr[3] = (__bf16)(sA[3] * kA.w);
    bfr[4] = (__bf16)(sB[0] * kB.x); bfr[5] = (__bf16)(sB[1] * kB.y);
    bfr[6] = (__bf16)(sB[2] * kB.z); bfr[7] = (__bf16)(sB[3] * kB.w);
    const bf16x8 afr = *(const bf16x8*)(ap + ks * 32);
    acc = __builtin_amdgcn_mfma_f32_16x16x32_bf16(afr, bfr, acc, 0, 0, 0);
  }
  // publish partials (2-way bank alias only — free)
  #pragma unroll
  for (int i = 0; i < 4; ++i) pacc[kq][et][q * 4 + i][ln] = acc[i];

  __syncthreads();                       // pacc ready

  // ---------- fused combine + similarity store + softmax (256 threads) ----------
  if (t < 256) {
    const int row = t >> 4, seg = t & 15;
    const int pe = seg >> 2, pc = (seg & 3) * 4;
    f32x4 p = *(const f32x4*)&pacc[0][pe][row][pc];
    #pragma unroll
    for (int k = 1; k < 4; ++k) {
      const f32x4 pk = *(const f32x4*)&pacc[k][pe][row][pc];
      p[0] += pk[0]; p[1] += pk[1]; p[2] += pk[2]; p[3] += pk[3];
    }
    const f32x4 ak4 = *(const f32x4*)&aklds[seg * 4];
    const float azr = azs[row];
    f32x4 s;
    #pragma unroll
    for (int j = 0; j < 4; ++j) {
      const float dist = azr + ak4[j] - 2.0f * p[j];
      s[j] = 1.0f / (1.0f + dist);
    }
    *(f32x4*)(out_sim + (size_t)(b0 + row) * E_N + seg * 4) = s;
    float mx = fmaxf(fmaxf(s[0], s[1]), fmaxf(s[2], s[3]));
    mx = fmaxf(mx, __shfl_xor(mx, 1));
    mx = fmaxf(mx, __shfl_xor(mx, 2));
    mx = fmaxf(mx, __shfl_xor(mx, 4));
    mx = fmaxf(mx, __shfl_xor(mx, 8));
    float v[4];
    float sum = 0.f;
    #pragma unroll
    for (int j = 0; j < 4; ++j) { v[j] = __expf(s[j] - mx); sum += v[j]; }
    sum += __shfl_xor(sum, 1);
    sum += __shfl_xor(sum, 2);
    sum += __shfl_xor(sum, 4);
    sum += __shfl_xor(sum, 8);
    const float inv = 1.0f / sum;
    bf16x4 wq;
    #pragma unroll
    for (int j = 0; j < 4; ++j) wq[j] = (__bf16)(v[j] * inv);
    *(bf16x4*)&wlds[row][seg * 4] = wq;
  }
  __syncthreads();                       // wlds ready

  // ---------- GEMM2: out[16 rows][1024] = w[16][64] @ keys[64][1024] ----------
  // B-frag = bf16(keys^T) via strided column loads (keys L2-resident).
  const bf16x8 a0 = *(const bf16x8*)&wlds[ln][q * 8];        // A: m=row, k=e
  const bf16x8 a1 = *(const bf16x8*)&wlds[ln][32 + q * 8];
  #pragma unroll
  for (int i = 0; i < 4; ++i) {
    const int dt = wave + 16 * i;
    const int d0 = dt * 16;
    const float* kcol = keys + d0 + ln;
    bf16x8 b0f, b1f;
    #pragma unroll
    for (int j = 0; j < 8; ++j) {
      b0f[j] = (__bf16)kcol[(size_t)(q * 8 + j) * D_N];
      b1f[j] = (__bf16)kcol[(size_t)(32 + q * 8 + j) * D_N];
    }
    f32x4 o = {0.f, 0.f, 0.f, 0.f};
    o = __builtin_amdgcn_mfma_f32_16x16x32_bf16(a0, b0f, o, 0, 0, 0);
    o = __builtin_amdgcn_mfma_f32_16x16x32_bf16(a1, b1f, o, 0, 0, 0);
    #pragma unroll
    for (int j = 0; j < 4; ++j)
      out_we[(size_t)(b0 + q * 4 + j) * D_N + d0 + ln] = o[j];
  }
}

extern "C" void kernel_launch(void* const* d_in, const int* in_sizes, int n_in,
                              void* d_out, int out_size, void* d_ws, size_t ws_size,
                              hipStream_t stream)
{
  const float* z    = (const float*)d_in[0];
  const float* keys = (const float*)d_in[1];
  const float* ls   = (const float*)d_in[2];
  float* out_sim = (float*)d_out;
  float* out_we  = out_sim + (size_t)B_N * E_N;
  fused_kernel<<<B_N / ROWS, 1024, 0, stream>>>(z, keys, ls, out_sim, out_we);
}

// Round 8
// 83.828 us; speedup vs baseline: 1.5042x; 1.0816x over previous
//
#include <hip/hip_runtime.h>
#include <hip/hip_bf16.h>

#define B_N 4096
#define E_N 64
#define D_N 1024
#define ROWS 16

typedef __bf16 bf16x8 __attribute__((ext_vector_type(8)));
typedef __bf16 bf16x4 __attribute__((ext_vector_type(4)));
typedef float f32x4 __attribute__((ext_vector_type(4)));

// ws layout (bytes):
// [0, 16384)           az_g   (4096 f32)  sum_d sinv*z^2 per row
// [16384, 16640)       ak     (64 f32)
// [16640, 147712)      sk_bf16 [64][1024]  (sigma_inv * keys, K-major)
// [147712, 278784)     kT_bf16 [1024][64]  (raw keys transposed)
// [1048576, 9437184)   zb_bf16 [4096][1024] (z converted to bf16)

// prep: blocks 0..63 expert duties; 64..79 transpose; 80..591 stream-convert
// 8 z-rows each (z f32 -> bf16 + az). Streaming work runs here at high HBM
// efficiency instead of on main's barrier-locked critical path.
__global__ __launch_bounds__(256) void prep_kernel(
    const float* __restrict__ keys, const float* __restrict__ lsig,
    const float* __restrict__ z,
    float* __restrict__ az_g, float* __restrict__ ak,
    __bf16* __restrict__ sk, __bf16* __restrict__ kT,
    __bf16* __restrict__ zb)
{
  __shared__ float red[4];
  __shared__ __bf16 tl[64][72];          // transpose tile, +8 pad
  const int bid = blockIdx.x;
  const int t = threadIdx.x;

  if (bid < 64) {
    // ---- per-expert: sk = sinv*keys (bf16), Ak = sum sinv*k^2 ----
    const int e = bid;
    const float4 k4 = *(const float4*)(keys + e * D_N + 4 * t);
    const float4 l4 = *(const float4*)(lsig + 4 * t);
    float4 s4;
    s4.x = expf(-l4.x); s4.y = expf(-l4.y); s4.z = expf(-l4.z); s4.w = expf(-l4.w);
    const float4 sk4 = make_float4(s4.x * k4.x, s4.y * k4.y, s4.z * k4.z, s4.w * k4.w);
    bf16x4 skb;
    skb[0] = (__bf16)sk4.x; skb[1] = (__bf16)sk4.y; skb[2] = (__bf16)sk4.z; skb[3] = (__bf16)sk4.w;
    *(bf16x4*)(sk + e * D_N + 4 * t) = skb;
    float p = sk4.x * k4.x + sk4.y * k4.y + sk4.z * k4.z + sk4.w * k4.w;
    #pragma unroll
    for (int off = 32; off > 0; off >>= 1) p += __shfl_down(p, off);
    if ((t & 63) == 0) red[t >> 6] = p;
    __syncthreads();
    if (t == 0) ak[e] = red[0] + red[1] + red[2] + red[3];
  } else if (bid < 80) {
    // ---- transpose: kT[d][e] = (bf16) keys[e][d], 64-d slab per block ----
    const int d0 = (bid - 64) * 64;
    #pragma unroll
    for (int p = 0; p < 4; ++p) {
      const int e  = p * 16 + (t >> 4);
      const int dd = (t & 15) * 4;
      const float4 k4 = *(const float4*)(keys + (size_t)e * D_N + d0 + dd);
      tl[dd + 0][e] = (__bf16)k4.x; tl[dd + 1][e] = (__bf16)k4.y;
      tl[dd + 2][e] = (__bf16)k4.z; tl[dd + 3][e] = (__bf16)k4.w;
    }
    __syncthreads();
    #pragma unroll
    for (int p = 0; p < 2; ++p) {
      const int dd = p * 32 + (t >> 3);
      const int l8 = t & 7;
      const bf16x8 v = *(const bf16x8*)&tl[dd][l8 * 8];
      *(bf16x8*)(kT + (size_t)(d0 + dd) * E_N + l8 * 8) = v;
    }
  } else {
    // ---- z stream-convert: 8 rows/block; az bitwise-matches old main ----
    const int zr0 = (bid - 80) * 8;
    const int zr  = t >> 5;              // row 0..7
    const int zc  = t & 31;
    const float* zrow = z + (size_t)(zr0 + zr) * D_N;
    __bf16* zorow = zb + (size_t)(zr0 + zr) * D_N;
    float az = 0.f;
    #pragma unroll
    for (int l = 0; l < 8; ++l) {
      const int c = zc * 4 + l * 128;    // same pattern as old main stage
      const float4 z4 = *(const float4*)(zrow + c);
      const float4 l4 = *(const float4*)(lsig + c);
      float4 s4;
      s4.x = __expf(-l4.x); s4.y = __expf(-l4.y);
      s4.z = __expf(-l4.z); s4.w = __expf(-l4.w);
      az += s4.x * z4.x * z4.x + s4.y * z4.y * z4.y
          + s4.z * z4.z * z4.z + s4.w * z4.w * z4.w;
      bf16x4 zbv;
      zbv[0] = (__bf16)z4.x; zbv[1] = (__bf16)z4.y;
      zbv[2] = (__bf16)z4.z; zbv[3] = (__bf16)z4.w;
      *(bf16x4*)(zorow + c) = zbv;
    }
    az += __shfl_xor(az, 1);  az += __shfl_xor(az, 2);
    az += __shfl_xor(az, 4);  az += __shfl_xor(az, 8);
    az += __shfl_xor(az, 16);
    if (zc == 0) az_g[zr0 + zr] = az;
  }
}

// main: verbatim 81.1us R3 structure, but stage is now a pure 32KB bf16 copy
// (no f32 reads, no sinv, no expf, no az reduce) — that work moved to prep.
__global__ __launch_bounds__(512) void main_kernel(
    const __bf16* __restrict__ zb, const float* __restrict__ az_g,
    const float* __restrict__ ak, const __bf16* __restrict__ sk,
    const __bf16* __restrict__ kT,
    float* __restrict__ out_sim, float* __restrict__ out_we)
{
  constexpr int ZS = D_N + 8;            // bf16 elems; 16B-aligned rows
  __shared__ __bf16 zlds[ROWS * ZS];     // 33 KB
  __shared__ float azs[ROWS];
  __shared__ float pacc[4][16][17];      // K-half partials, +1 pad
  __shared__ float simb[ROWS][68];       // +4 pad
  __shared__ __bf16 wlds[ROWS][72];      // +8 pad

  const int t  = threadIdx.x;
  const int b0 = blockIdx.x * ROWS;

  const int wave = t >> 6;               // 0..7
  const int lane = t & 63;
  const int ln = lane & 15;
  const int q  = lane >> 4;
  const int et = wave & 3;               // expert tile 0..3
  const int kh = wave >> 2;              // K-half 0..1

  // early L2 load, latency hidden under stage phase
  const float akv = ak[et * 16 + ln];

  // ---------- stage zb (bf16) -> LDS; pure copy ----------
  const int sr = t >> 5;                 // row 0..15
  const int sc = t & 31;
  const __bf16* zrow = zb + (size_t)(b0 + sr) * D_N;
  #pragma unroll
  for (int l = 0; l < 4; ++l) {
    const int c = sc * 8 + l * 256;
    const bf16x8 v = *(const bf16x8*)(zrow + c);
    *(bf16x8*)(&zlds[sr * ZS + c]) = v;
  }
  if (t < ROWS) azs[t] = az_g[b0 + t];

  // prefetch first 4 sk B-frags (global/L2, no LDS dependency)
  const __bf16* bp = sk + (size_t)(et * 16 + ln) * D_N + kh * 512 + q * 8;
  const bf16x8 bpf0 = *(const bf16x8*)(bp);
  const bf16x8 bpf1 = *(const bf16x8*)(bp + 32);
  const bf16x8 bpf2 = *(const bf16x8*)(bp + 64);
  const bf16x8 bpf3 = *(const bf16x8*)(bp + 96);

  __syncthreads();                       // zlds + azs ready

  // ---------- GEMM1 (split-K): each wave does 16 experts x 512 K ----------
  const __bf16* ap = &zlds[ln * ZS + kh * 512 + q * 8];
  f32x4 acc = {0.f, 0.f, 0.f, 0.f};
  {
    const bf16x8 a0 = *(const bf16x8*)(ap);
    acc = __builtin_amdgcn_mfma_f32_16x16x32_bf16(a0, bpf0, acc, 0, 0, 0);
    const bf16x8 a1 = *(const bf16x8*)(ap + 32);
    acc = __builtin_amdgcn_mfma_f32_16x16x32_bf16(a1, bpf1, acc, 0, 0, 0);
    const bf16x8 a2 = *(const bf16x8*)(ap + 64);
    acc = __builtin_amdgcn_mfma_f32_16x16x32_bf16(a2, bpf2, acc, 0, 0, 0);
    const bf16x8 a3 = *(const bf16x8*)(ap + 96);
    acc = __builtin_amdgcn_mfma_f32_16x16x32_bf16(a3, bpf3, acc, 0, 0, 0);
  }
  #pragma unroll
  for (int ks = 4; ks < 16; ++ks) {
    const bf16x8 bfr = *(const bf16x8*)(bp + ks * 32);
    const bf16x8 afr = *(const bf16x8*)(ap + ks * 32);
    acc = __builtin_amdgcn_mfma_f32_16x16x32_bf16(afr, bfr, acc, 0, 0, 0);
  }

  // K-half 1 publishes partials
  if (kh) {
    #pragma unroll
    for (int i = 0; i < 4; ++i) pacc[et][q * 4 + i][ln] = acc[i];
  }

  // prefetch GEMM2's first B-frag group (global kT, no LDS dependency)
  const __bf16* kp0 = kT + (size_t)(wave * 16 + ln) * E_N + q * 8;
  const bf16x8 pb0 = *(const bf16x8*)(kp0);
  const bf16x8 pb1 = *(const bf16x8*)(kp0 + 32);

  __syncthreads();                       // pacc ready

  // K-half 0 combines and writes similarity
  if (!kh) {
    #pragma unroll
    for (int i = 0; i < 4; ++i) {
      const int row = q * 4 + i;         // C: row = quad*4+reg, col = lane&15
      const float dot = acc[i] + pacc[et][row][ln];
      const float dist = azs[row] + akv - 2.0f * dot;
      simb[row][et * 16 + ln] = 1.0f / (1.0f + dist);
    }
  }
  __syncthreads();                       // simb ready

  // ---------- similarity -> global (coalesced float4); overlaps softmax ----------
  if (t < 256) {
    const float4 sv = *(const float4*)&simb[t >> 4][(t & 15) * 4];
    *(float4*)(out_sim + (size_t)(b0 + (t >> 4)) * E_N + (t & 15) * 4) = sv;
  }

  // ---------- softmax over e (threads 0..63: 4 lanes per row) ----------
  if (t < 64) {
    const int row = t >> 2, seg = t & 3;
    float v[16];
    #pragma unroll
    for (int i = 0; i < 16; ++i) v[i] = simb[row][seg * 16 + i];
    float mx = v[0];
    #pragma unroll
    for (int i = 1; i < 16; ++i) mx = fmaxf(mx, v[i]);
    mx = fmaxf(mx, __shfl_xor(mx, 1));
    mx = fmaxf(mx, __shfl_xor(mx, 2));
    float sum = 0.f;
    #pragma unroll
    for (int i = 0; i < 16; ++i) { v[i] = __expf(v[i] - mx); sum += v[i]; }
    sum += __shfl_xor(sum, 1);
    sum += __shfl_xor(sum, 2);
    const float inv = 1.0f / sum;
    #pragma unroll
    for (int i = 0; i < 16; ++i) wlds[row][seg * 16 + i] = (__bf16)(v[i] * inv);
  }
  __syncthreads();                       // wlds ready

  // ---------- GEMM2: out[16 rows][1024] = w[16][64] @ keys[64][1024] ----------
  const bf16x8 a0 = *(const bf16x8*)&wlds[ln][q * 8];        // A: m=row, k=e
  const bf16x8 a1 = *(const bf16x8*)&wlds[ln][32 + q * 8];
  #pragma unroll
  for (int i = 0; i < 8; ++i) {
    const int dt = wave + 8 * i;
    const int d0 = dt * 16;
    bf16x8 b0f, b1f;
    if (i == 0) { b0f = pb0; b1f = pb1; }
    else {
      const __bf16* kp = kT + (size_t)(d0 + ln) * E_N + q * 8;
      b0f = *(const bf16x8*)(kp);
      b1f = *(const bf16x8*)(kp + 32);
    }
    f32x4 o = {0.f, 0.f, 0.f, 0.f};
    o = __builtin_amdgcn_mfma_f32_16x16x32_bf16(a0, b0f, o, 0, 0, 0);
    o = __builtin_amdgcn_mfma_f32_16x16x32_bf16(a1, b1f, o, 0, 0, 0);
    #pragma unroll
    for (int j = 0; j < 4; ++j)
      out_we[(size_t)(b0 + q * 4 + j) * D_N + d0 + ln] = o[j];
  }
}

extern "C" void kernel_launch(void* const* d_in, const int* in_sizes, int n_in,
                              void* d_out, int out_size, void* d_ws, size_t ws_size,
                              hipStream_t stream)
{
  const float* z    = (const float*)d_in[0];
  const float* keys = (const float*)d_in[1];
  const float* ls   = (const float*)d_in[2];
  float* out_sim = (float*)d_out;
  float* out_we  = out_sim + (size_t)B_N * E_N;
  char* ws = (char*)d_ws;
  float*  az_g = (float*)(ws);
  float*  ak   = (float*)(ws + 16384);
  __bf16* sk   = (__bf16*)(ws + 16640);
  __bf16* kT   = (__bf16*)(ws + 147712);
  __bf16* zb   = (__bf16*)(ws + 1048576);
  prep_kernel<<<80 + B_N / 8, 256, 0, stream>>>(keys, ls, z, az_g, ak, sk, kT, zb);
  main_kernel<<<B_N / ROWS, 512, 0, stream>>>(zb, az_g, ak, sk, kT, out_sim, out_we);
}

// Round 9
// 82.037 us; speedup vs baseline: 1.5370x; 1.0218x over previous
//
#include <hip/hip_runtime.h>
#include <hip/hip_bf16.h>

#define B_N 4096
#define E_N 64
#define D_N 1024
#define ROWS 16

typedef __bf16 bf16x8 __attribute__((ext_vector_type(8)));
typedef __bf16 bf16x4 __attribute__((ext_vector_type(4)));
typedef float f32x4 __attribute__((ext_vector_type(4)));

// ws layout (bytes):
// [0, 4096)        sinv   (1024 f32)
// [4096, 4352)     Ak     (64 f32)
// [4352, 135424)   sk_bf16 [64][1024]   (sigma_inv * keys, K-major)
// [135424, 266496) kT_bf16 [1024][64]   (raw keys transposed, K(=e)-major)

__global__ __launch_bounds__(256) void prep_kernel(
    const float* __restrict__ keys, const float* __restrict__ lsig,
    float* __restrict__ sinv, float* __restrict__ ak,
    __bf16* __restrict__ sk, __bf16* __restrict__ kT)
{
  __shared__ float red[4];
  __shared__ __bf16 tl[64][72];          // transpose tile, +8 pad
  const int bid = blockIdx.x;
  const int t = threadIdx.x;

  if (bid < 64) {
    // ---- per-expert: sinv, sk = sinv*keys (bf16), Ak = sum sinv*k^2 ----
    const int e = bid;
    const float4 k4 = *(const float4*)(keys + e * D_N + 4 * t);
    const float4 l4 = *(const float4*)(lsig + 4 * t);
    float4 s4;
    s4.x = expf(-l4.x); s4.y = expf(-l4.y); s4.z = expf(-l4.z); s4.w = expf(-l4.w);
    if (e == 0) *(float4*)(sinv + 4 * t) = s4;
    const float4 sk4 = make_float4(s4.x * k4.x, s4.y * k4.y, s4.z * k4.z, s4.w * k4.w);
    bf16x4 skb;
    skb[0] = (__bf16)sk4.x; skb[1] = (__bf16)sk4.y; skb[2] = (__bf16)sk4.z; skb[3] = (__bf16)sk4.w;
    *(bf16x4*)(sk + e * D_N + 4 * t) = skb;
    float p = sk4.x * k4.x + sk4.y * k4.y + sk4.z * k4.z + sk4.w * k4.w;
    #pragma unroll
    for (int off = 32; off > 0; off >>= 1) p += __shfl_down(p, off);
    if ((t & 63) == 0) red[t >> 6] = p;
    __syncthreads();
    if (t == 0) ak[e] = red[0] + red[1] + red[2] + red[3];
  } else {
    // ---- transpose: kT[d][e] = (bf16) keys[e][d], 64-d slab per block ----
    const int d0 = (bid - 64) * 64;
    #pragma unroll
    for (int p = 0; p < 4; ++p) {
      const int e  = p * 16 + (t >> 4);
      const int dd = (t & 15) * 4;
      const float4 k4 = *(const float4*)(keys + (size_t)e * D_N + d0 + dd);
      tl[dd + 0][e] = (__bf16)k4.x; tl[dd + 1][e] = (__bf16)k4.y;
      tl[dd + 2][e] = (__bf16)k4.z; tl[dd + 3][e] = (__bf16)k4.w;
    }
    __syncthreads();
    #pragma unroll
    for (int p = 0; p < 2; ++p) {
      const int dd = p * 32 + (t >> 3);
      const int l8 = t & 7;
      const bf16x8 v = *(const bf16x8*)&tl[dd][l8 * 8];
      *(bf16x8*)(kT + (size_t)(d0 + dd) * E_N + l8 * 8) = v;
    }
  }
}

// 8-wave block, ROWS=16, grid=256 (one block/CU). Session-best configuration
// (81.1us): split-K GEMM1 across wave pairs, LDS partial combine, fused
// softmax, 8 d-tiles/wave GEMM2. Occupancy >2 waves/SIMD, register
// prefetching across barriers, cooperative fusion, and on-the-fly operand
// construction were each tried and all regressed or were neutral.
__global__ __launch_bounds__(512) void main_kernel(
    const float* __restrict__ z, const float* __restrict__ sinv,
    const float* __restrict__ ak, const __bf16* __restrict__ sk,
    const __bf16* __restrict__ kT,
    float* __restrict__ out_sim, float* __restrict__ out_we)
{
  constexpr int ZS = D_N + 8;            // bf16 elems; 16B-aligned rows
  __shared__ __bf16 zlds[ROWS * ZS];     // 33 KB
  __shared__ float azs[ROWS];
  __shared__ float pacc[4][16][17];      // K-half partials, +1 pad
  __shared__ float simb[ROWS][68];       // +4 pad
  __shared__ __bf16 wlds[ROWS][72];      // +8 pad

  const int t  = threadIdx.x;
  const int b0 = blockIdx.x * ROWS;

  const int wave = t >> 6;               // 0..7
  const int lane = t & 63;
  const int ln = lane & 15;
  const int q  = lane >> 4;
  const int et = wave & 3;               // expert tile 0..3
  const int kh = wave >> 2;              // K-half 0..1

  // early L2 load, latency hidden under stage phase
  const float akv = ak[et * 16 + ln];

  // ---------- stage z -> bf16 LDS; Az = sum s*z^2 (32 threads per row) ----------
  const int sr = t >> 5;                 // row 0..15
  const int sc = t & 31;
  const float* zrow = z + (size_t)(b0 + sr) * D_N;
  float az = 0.f;
  #pragma unroll
  for (int l = 0; l < 8; ++l) {
    const int c = sc * 4 + l * 128;
    const float4 z4 = *(const float4*)(zrow + c);
    const float4 s4 = *(const float4*)(sinv + c);
    az += s4.x * z4.x * z4.x + s4.y * z4.y * z4.y + s4.z * z4.z * z4.z + s4.w * z4.w * z4.w;
    bf16x4 zb;
    zb[0] = (__bf16)z4.x; zb[1] = (__bf16)z4.y; zb[2] = (__bf16)z4.z; zb[3] = (__bf16)z4.w;
    *(bf16x4*)(&zlds[sr * ZS + c]) = zb;
  }
  // reduce across the 32 lanes of this row (xor<=16 stays inside the group)
  az += __shfl_xor(az, 1);  az += __shfl_xor(az, 2);
  az += __shfl_xor(az, 4);  az += __shfl_xor(az, 8);
  az += __shfl_xor(az, 16);
  if (sc == 0) azs[sr] = az;

  // prefetch first 4 sk B-frags (global/L2, no LDS dependency)
  const __bf16* bp = sk + (size_t)(et * 16 + ln) * D_N + kh * 512 + q * 8;
  const bf16x8 bpf0 = *(const bf16x8*)(bp);
  const bf16x8 bpf1 = *(const bf16x8*)(bp + 32);
  const bf16x8 bpf2 = *(const bf16x8*)(bp + 64);
  const bf16x8 bpf3 = *(const bf16x8*)(bp + 96);

  __syncthreads();                       // zlds + azs ready

  // ---------- GEMM1 (split-K): each wave does 16 experts x 512 K ----------
  const __bf16* ap = &zlds[ln * ZS + kh * 512 + q * 8];
  f32x4 acc = {0.f, 0.f, 0.f, 0.f};
  {
    const bf16x8 a0 = *(const bf16x8*)(ap);
    acc = __builtin_amdgcn_mfma_f32_16x16x32_bf16(a0, bpf0, acc, 0, 0, 0);
    const bf16x8 a1 = *(const bf16x8*)(ap + 32);
    acc = __builtin_amdgcn_mfma_f32_16x16x32_bf16(a1, bpf1, acc, 0, 0, 0);
    const bf16x8 a2 = *(const bf16x8*)(ap + 64);
    acc = __builtin_amdgcn_mfma_f32_16x16x32_bf16(a2, bpf2, acc, 0, 0, 0);
    const bf16x8 a3 = *(const bf16x8*)(ap + 96);
    acc = __builtin_amdgcn_mfma_f32_16x16x32_bf16(a3, bpf3, acc, 0, 0, 0);
  }
  #pragma unroll
  for (int ks = 4; ks < 16; ++ks) {
    const bf16x8 bfr = *(const bf16x8*)(bp + ks * 32);
    const bf16x8 afr = *(const bf16x8*)(ap + ks * 32);
    acc = __builtin_amdgcn_mfma_f32_16x16x32_bf16(afr, bfr, acc, 0, 0, 0);
  }

  // K-half 1 publishes partials
  if (kh) {
    #pragma unroll
    for (int i = 0; i < 4; ++i) pacc[et][q * 4 + i][ln] = acc[i];
  }

  // prefetch GEMM2's first B-frag group (global kT, no LDS dependency)
  const __bf16* kp0 = kT + (size_t)(wave * 16 + ln) * E_N + q * 8;
  const bf16x8 pb0 = *(const bf16x8*)(kp0);
  const bf16x8 pb1 = *(const bf16x8*)(kp0 + 32);

  __syncthreads();                       // pacc ready

  // K-half 0 combines and writes similarity
  if (!kh) {
    #pragma unroll
    for (int i = 0; i < 4; ++i) {
      const int row = q * 4 + i;         // C: row = quad*4+reg, col = lane&15
      const float dot = acc[i] + pacc[et][row][ln];
      const float dist = azs[row] + akv - 2.0f * dot;
      simb[row][et * 16 + ln] = 1.0f / (1.0f + dist);
    }
  }
  __syncthreads();                       // simb ready

  // ---------- similarity -> global (coalesced float4); overlaps softmax ----------
  if (t < 256) {
    const float4 sv = *(const float4*)&simb[t >> 4][(t & 15) * 4];
    *(float4*)(out_sim + (size_t)(b0 + (t >> 4)) * E_N + (t & 15) * 4) = sv;
  }

  // ---------- softmax over e (threads 0..63: 4 lanes per row) ----------
  if (t < 64) {
    const int row = t >> 2, seg = t & 3;
    float v[16];
    #pragma unroll
    for (int i = 0; i < 16; ++i) v[i] = simb[row][seg * 16 + i];
    float mx = v[0];
    #pragma unroll
    for (int i = 1; i < 16; ++i) mx = fmaxf(mx, v[i]);
    mx = fmaxf(mx, __shfl_xor(mx, 1));
    mx = fmaxf(mx, __shfl_xor(mx, 2));
    float sum = 0.f;
    #pragma unroll
    for (int i = 0; i < 16; ++i) { v[i] = __expf(v[i] - mx); sum += v[i]; }
    sum += __shfl_xor(sum, 1);
    sum += __shfl_xor(sum, 2);
    const float inv = 1.0f / sum;
    #pragma unroll
    for (int i = 0; i < 16; ++i) wlds[row][seg * 16 + i] = (__bf16)(v[i] * inv);
  }
  __syncthreads();                       // wlds ready

  // ---------- GEMM2: out[16 rows][1024] = w[16][64] @ keys[64][1024] ----------
  const bf16x8 a0 = *(const bf16x8*)&wlds[ln][q * 8];        // A: m=row, k=e
  const bf16x8 a1 = *(const bf16x8*)&wlds[ln][32 + q * 8];
  #pragma unroll
  for (int i = 0; i < 8; ++i) {
    const int dt = wave + 8 * i;
    const int d0 = dt * 16;
    bf16x8 b0f, b1f;
    if (i == 0) { b0f = pb0; b1f = pb1; }
    else {
      const __bf16* kp = kT + (size_t)(d0 + ln) * E_N + q * 8;
      b0f = *(const bf16x8*)(kp);
      b1f = *(const bf16x8*)(kp + 32);
    }
    f32x4 o = {0.f, 0.f, 0.f, 0.f};
    o = __builtin_amdgcn_mfma_f32_16x16x32_bf16(a0, b0f, o, 0, 0, 0);
    o = __builtin_amdgcn_mfma_f32_16x16x32_bf16(a1, b1f, o, 0, 0, 0);
    #pragma unroll
    for (int j = 0; j < 4; ++j)
      out_we[(size_t)(b0 + q * 4 + j) * D_N + d0 + ln] = o[j];
  }
}

extern "C" void kernel_launch(void* const* d_in, const int* in_sizes, int n_in,
                              void* d_out, int out_size, void* d_ws, size_t ws_size,
                              hipStream_t stream)
{
  const float* z    = (const float*)d_in[0];
  const float* keys = (const float*)d_in[1];
  const float* ls   = (const float*)d_in[2];
  float* out_sim = (float*)d_out;
  float* out_we  = out_sim + (size_t)B_N * E_N;
  char* ws = (char*)d_ws;
  float*  sinv = (float*)(ws);
  float*  ak   = (float*)(ws + 4096);
  __bf16* sk   = (__bf16*)(ws + 4352);
  __bf16* kT   = (__bf16*)(ws + 135424);
  prep_kernel<<<80, 256, 0, stream>>>(keys, ls, sinv, ak, sk, kT);
  main_kernel<<<B_N / ROWS, 512, 0, stream>>>(z, sinv, ak, sk, kT, out_sim, out_we);
}